// Round 3
// baseline (819.421 us; speedup 1.0000x reference)
//
#include <hip/hip_runtime.h>
#include <hip/hip_bf16.h>

typedef unsigned short u16;
typedef __attribute__((ext_vector_type(8))) short short8;
typedef __attribute__((ext_vector_type(4))) float f4;

static __device__ __forceinline__ float b2f(u16 u) {
    union { unsigned int i; float f; } x; x.i = ((unsigned int)u) << 16; return x.f;
}
static __device__ __forceinline__ u16 f2b(float f) {
    union { float f; unsigned int i; } x; x.f = f;
    unsigned int r = x.i + 0x7fffu + ((x.i >> 16) & 1u);
    return (u16)(r >> 16);
}
static __device__ __forceinline__ float wave_reduce_sum(float v) {
    #pragma unroll
    for (int off = 32; off > 0; off >>= 1) v += __shfl_down(v, off, 64);
    return v;
}

// ---------------------------------------------------------------- f32 -> bf16 convert
__global__ __launch_bounds__(256) void conv_f32_bf16(
    const float* __restrict__ src, u16* __restrict__ dst, int n)
{
    int i = (blockIdx.x * 256 + threadIdx.x) * 4;
    if (i >= n) return;
    float4 v = *(const float4*)(src + i);
    union { u16 u[4]; uint2 d; } o;
    o.u[0] = f2b(v.x); o.u[1] = f2b(v.y); o.u[2] = f2b(v.z); o.u[3] = f2b(v.w);
    *(uint2*)(dst + i) = o.d;
}

// ---------------------------------------------------------------- transpose f32 -> bf16
// out[n*out_stride + k_off + k] = bf16(in[k*N + n])
__global__ __launch_bounds__(256) void transpose_k(
    const float* __restrict__ in, u16* __restrict__ out,
    int K, int N, int out_stride, int k_off)
{
    __shared__ float t[32][33];
    int kb = blockIdx.x * 32, nb = blockIdx.y * 32;
    int tx = threadIdx.x, ty = threadIdx.y; // blockDim (32,8)
    #pragma unroll
    for (int i = 0; i < 4; i++)
        t[ty + i * 8][tx] = in[(size_t)(kb + ty + i * 8) * N + nb + tx];
    __syncthreads();
    #pragma unroll
    for (int i = 0; i < 4; i++)
        out[(size_t)(nb + ty + i * 8) * out_stride + k_off + kb + tx] =
            f2b(t[tx][ty + i * 8]);
}

// ---------------------------------------------------------------- MFMA GEMM
// C[m,n] = sum_k A0[m,0:K0]*Bt[n,0:K0] + A1[m,0:K1]*Bt[n,K0:K0+K1] + bias (f32)
// epi 0: none; 1: C *= E[(m/m_div), n]; 2: C = g[m]*mi1[m,n] + (1-g[m])*C
#define BM 128
#define BN 128
#define BKT 32
#define BKP 40

__global__ __launch_bounds__(256) void gemm_mfma(
    const u16* __restrict__ A0, const u16* __restrict__ A1,
    int M, int K0, int K1, int N,
    const u16* __restrict__ Bt,
    const float* __restrict__ bias0, const float* __restrict__ bias1,
    int epi_mode, const float* __restrict__ E, int m_div,
    const float* __restrict__ gate, const float* __restrict__ mi1,
    void* __restrict__ Cout, int out_f32)
{
    __shared__ __align__(16) short As[BM * BKP];
    __shared__ __align__(16) short Bs[BN * BKP];
    int tid  = threadIdx.x;
    int wave = tid >> 6, lane = tid & 63;
    int wm = wave >> 1, wn = wave & 1;
    int lrow = lane & 15, quad = lane >> 4;
    int bm0 = blockIdx.y * BM, bn0 = blockIdx.x * BN;
    int Ktot = K0 + K1;

    f4 acc[4][4];
    #pragma unroll
    for (int i = 0; i < 4; i++)
        #pragma unroll
        for (int j = 0; j < 4; j++)
            acc[i][j] = (f4){0.f, 0.f, 0.f, 0.f};

    for (int k0 = 0; k0 < Ktot; k0 += BKT) {
        #pragma unroll
        for (int i = 0; i < 2; i++) {
            int idx = i * 256 + tid;
            int row = idx >> 2, ch = idx & 3;
            int k = k0 + ch * 8;
            int am = bm0 + row; if (am >= M) am = M - 1;  // clamp (dup reads ok)
            const u16* src;
            if (k < K0) src = A0 + (size_t)am * K0 + k;
            else        src = A1 + (size_t)am * K1 + (k - K0);
            *(uint4*)&As[row * BKP + ch * 8] = *(const uint4*)src;
            *(uint4*)&Bs[row * BKP + ch * 8] =
                *(const uint4*)(Bt + (size_t)(bn0 + row) * Ktot + k);
        }
        __syncthreads();
        short8 af[4], bfr[4];
        #pragma unroll
        for (int mt = 0; mt < 4; mt++)
            af[mt] = *(const short8*)&As[(wm * 64 + mt * 16 + lrow) * BKP + quad * 8];
        #pragma unroll
        for (int nt = 0; nt < 4; nt++)
            bfr[nt] = *(const short8*)&Bs[(wn * 64 + nt * 16 + lrow) * BKP + quad * 8];
        #pragma unroll
        for (int mt = 0; mt < 4; mt++)
            #pragma unroll
            for (int nt = 0; nt < 4; nt++)
                acc[mt][nt] = __builtin_amdgcn_mfma_f32_16x16x32_bf16(
                    af[mt], bfr[nt], acc[mt][nt], 0, 0, 0);
        __syncthreads();
    }

    #pragma unroll
    for (int nt = 0; nt < 4; nt++) {
        int n = bn0 + wn * 64 + nt * 16 + lrow;
        float bv = 0.f;
        if (bias0) bv += bias0[n];
        if (bias1) bv += bias1[n];
        #pragma unroll
        for (int mt = 0; mt < 4; mt++) {
            #pragma unroll
            for (int r = 0; r < 4; r++) {
                int m = bm0 + wm * 64 + mt * 16 + quad * 4 + r;
                if (m >= M) continue;
                float v = acc[mt][nt][r] + bv;
                if (epi_mode == 1) {
                    v *= E[(size_t)(m / m_div) * N + n];
                } else if (epi_mode == 2) {
                    float g = gate[m];
                    v = g * mi1[(size_t)m * N + n] + (1.f - g) * v;
                }
                if (out_f32) ((float*)Cout)[(size_t)m * N + n] = v;
                else         ((u16*)Cout)[(size_t)m * N + n] = f2b(v);
            }
        }
    }
}

// ---------------------------------------------------------------- control attention
// per b: cai[s] = sum_d cqi[b,d]*cws[b,s,d]*Wcai[d] + bcai; softmax_s; ci = sum_s p*cws
__global__ __launch_bounds__(256) void control_attn(
    const float* __restrict__ cqi, const float* __restrict__ cws,
    const float* __restrict__ Wcai, const float* __restrict__ bcai,
    float* __restrict__ ci_f32, float* __restrict__ ci_out)
{
    int b = blockIdx.x, tid = threadIdx.x;
    __shared__ float tW[512];
    __shared__ float p[128];
    __shared__ float inv_l;
    for (int d = tid; d < 512; d += 256)
        tW[d] = cqi[(size_t)b * 512 + d] * Wcai[d];
    __syncthreads();
    int wave = tid >> 6, lane = tid & 63;
    const float* cwsb = cws + (size_t)b * 128 * 512;
    for (int s = wave; s < 128; s += 4) {
        const float* row = cwsb + (size_t)s * 512 + lane * 8;
        float acc = 0.f;
        #pragma unroll
        for (int j = 0; j < 8; j++) acc += tW[lane * 8 + j] * row[j];
        acc = wave_reduce_sum(acc);
        if (lane == 0) p[s] = acc + bcai[0];
    }
    __syncthreads();
    if (tid == 0) {
        float m = -1e30f;
        for (int s = 0; s < 128; s++) m = fmaxf(m, p[s]);
        float l = 0.f;
        for (int s = 0; s < 128; s++) { float e = __expf(p[s] - m); p[s] = e; l += e; }
        inv_l = 1.f / l;
    }
    __syncthreads();
    float inv = inv_l;
    for (int d = tid; d < 512; d += 256) {
        float acc = 0.f;
        for (int s = 0; s < 128; s++) acc += p[s] * cwsb[(size_t)s * 512 + d];
        acc *= inv;
        ci_f32[(size_t)b * 512 + d] = acc;
        ci_out[(size_t)b * 512 + d] = acc;
    }
}

// ---------------------------------------------------------------- read reduce
// per (b,d): softmax over H of rai, then softmax over W of those probs, dot with K
__global__ __launch_bounds__(256) void read_reduce(
    const u16* __restrict__ rai, const float* __restrict__ Kin, u16* __restrict__ ri)
{
    int b = blockIdx.x >> 1;
    int d = ((blockIdx.x & 1) << 8) + threadIdx.x;
    const u16* rb = rai + (size_t)b * 196 * 512 + d;
    const float* kb = Kin + (size_t)b * 196 * 512 + d;
    float m1[14], il1[14];
    #pragma unroll
    for (int w = 0; w < 14; w++) {
        float mm = -1e30f;
        #pragma unroll
        for (int h = 0; h < 14; h++) mm = fmaxf(mm, b2f(rb[(size_t)(h * 14 + w) * 512]));
        float ss = 0.f;
        #pragma unroll
        for (int h = 0; h < 14; h++) ss += __expf(b2f(rb[(size_t)(h * 14 + w) * 512]) - mm);
        m1[w] = mm; il1[w] = 1.f / ss;
    }
    // second softmax over W of probabilities p in (0,1] -> no max-shift needed
    float il2[14];
    #pragma unroll
    for (int h = 0; h < 14; h++) {
        float ss = 0.f;
        #pragma unroll
        for (int w = 0; w < 14; w++) {
            float pv = __expf(b2f(rb[(size_t)(h * 14 + w) * 512]) - m1[w]) * il1[w];
            ss += __expf(pv);
        }
        il2[h] = 1.f / ss;
    }
    float acc = 0.f;
    #pragma unroll
    for (int h = 0; h < 14; h++) {
        #pragma unroll
        for (int w = 0; w < 14; w++) {
            float pv = __expf(b2f(rb[(size_t)(h * 14 + w) * 512]) - m1[w]) * il1[w];
            acc += __expf(pv) * il2[h] * kb[(size_t)(h * 14 + w) * 512];
        }
    }
    ri[(size_t)b * 512 + d] = f2b(acc);
}

// ---------------------------------------------------------------- write attention + gate
__global__ __launch_bounds__(256) void write_attn(
    const float* __restrict__ ci_f32, const float* __restrict__ C_past,
    const float* __restrict__ M_past,
    const float* __restrict__ Wwcc, const float* __restrict__ bwcc,
    const float* __restrict__ Wwci, const float* __restrict__ bwci,
    u16* __restrict__ mi_sa, float* __restrict__ gate)
{
    int b = blockIdx.x, tid = threadIdx.x;
    __shared__ float c[512];
    __shared__ float pt[12];
    __shared__ float red[256];
    for (int d = tid; d < 512; d += 256) c[d] = ci_f32[(size_t)b * 512 + d];
    __syncthreads();
    float g = 0.f;
    for (int d = tid; d < 512; d += 256) g += c[d] * Wwci[d];
    red[tid] = g;
    __syncthreads();
    for (int s = 128; s > 0; s >>= 1) {
        if (tid < s) red[tid] += red[tid + s];
        __syncthreads();
    }
    int wave = tid >> 6, lane = tid & 63;
    const float* cp = C_past + (size_t)b * 12 * 512;
    for (int t = wave; t < 12; t += 4) {
        float acc = 0.f;
        #pragma unroll
        for (int j = 0; j < 8; j++) {
            int d = lane * 8 + j;
            acc += c[d] * Wwcc[d] * cp[(size_t)t * 512 + d];
        }
        acc = wave_reduce_sum(acc);
        if (lane == 0) pt[t] = acc + bwcc[0];
    }
    __syncthreads();
    if (tid == 0) {
        float m = -1e30f;
        for (int t = 0; t < 12; t++) m = fmaxf(m, pt[t]);
        float l = 0.f;
        for (int t = 0; t < 12; t++) { float e = __expf(pt[t] - m); pt[t] = e; l += e; }
        float invl = 1.f / l;
        for (int t = 0; t < 12; t++) pt[t] *= invl;
        gate[b] = 1.f / (1.f + __expf(-(red[0] + bwci[0])));
    }
    __syncthreads();
    const float* mp = M_past + (size_t)b * 12 * 512;
    for (int d = tid; d < 512; d += 256) {
        float acc = 0.f;
        #pragma unroll
        for (int t = 0; t < 12; t++) acc += pt[t] * mp[(size_t)t * 512 + d];
        mi_sa[(size_t)b * 512 + d] = f2b(acc);
    }
}

// ---------------------------------------------------------------- launch
extern "C" void kernel_launch(void* const* d_in, const int* in_sizes, int n_in,
                              void* d_out, int out_size, void* d_ws, size_t ws_size,
                              hipStream_t stream) {
    (void)in_sizes; (void)n_in; (void)out_size;
    const int B = 256, D = 512, HW = 196;

    const float* ci_1   = (const float*)d_in[0];
    const float* mi_1   = (const float*)d_in[1];
    const float* q      = (const float*)d_in[2];
    const float* cws    = (const float*)d_in[3];
    const float* Kin    = (const float*)d_in[4];
    const float* C_past = (const float*)d_in[5];
    const float* M_past = (const float*)d_in[6];
    const float* W_cq   = (const float*)d_in[7];
    const float* b_cq   = (const float*)d_in[8];
    const float* W_cqi  = (const float*)d_in[9];
    const float* b_cqi  = (const float*)d_in[10];
    const float* W_cai  = (const float*)d_in[11];
    const float* b_cai  = (const float*)d_in[12];
    const float* W_rm   = (const float*)d_in[13];
    const float* b_rm   = (const float*)d_in[14];
    const float* W_rk   = (const float*)d_in[15];
    const float* b_rk   = (const float*)d_in[16];
    const float* W_rik  = (const float*)d_in[17];
    const float* b_rik  = (const float*)d_in[18];
    const float* W_rci  = (const float*)d_in[19];
    const float* b_rci  = (const float*)d_in[20];
    const float* W_wrm  = (const float*)d_in[21];
    const float* b_wrm  = (const float*)d_in[22];
    const float* W_wcc  = (const float*)d_in[23];
    const float* b_wcc  = (const float*)d_in[24];
    const float* W_wsa  = (const float*)d_in[25];
    const float* b_wsa  = (const float*)d_in[26];
    const float* W_winfo= (const float*)d_in[27];
    const float* b_winfo= (const float*)d_in[28];
    const float* W_wci  = (const float*)d_in[29];
    const float* b_wci  = (const float*)d_in[30];

    float* out_ci = (float*)d_out;
    float* out_mi = (float*)d_out + (size_t)B * D;

    char* ws = (char*)d_ws;
    size_t off = 0;
    auto alloc = [&](size_t bytes) -> void* {
        void* p = ws + off; off += (bytes + 255) & ~(size_t)255; return p;
    };
    u16* wt_cq    = (u16*)alloc((size_t)D * D * 2);
    u16* wt_cqi   = (u16*)alloc((size_t)D * 2 * D * 2);
    u16* wt_rm    = (u16*)alloc((size_t)D * D * 2);
    u16* wt_rk    = (u16*)alloc((size_t)D * D * 2);
    u16* wt_rik   = (u16*)alloc((size_t)D * 2 * D * 2);
    u16* wt_rci   = (u16*)alloc((size_t)D * D * 2);
    u16* wt_wrm   = (u16*)alloc((size_t)D * 2 * D * 2);
    u16* wt_wsi   = (u16*)alloc((size_t)D * 2 * D * 2);
    u16* qb       = (u16*)alloc((size_t)B * D * 2);   // bf16(q)
    u16* cib      = (u16*)alloc((size_t)B * D * 2);   // bf16(ci_1)
    u16* mib      = (u16*)alloc((size_t)B * D * 2);   // bf16(mi_1)
    u16* qi_buf   = (u16*)alloc((size_t)B * D * 2);
    float* cqi_f32= (float*)alloc((size_t)B * D * 4);
    float* rm_f32 = (float*)alloc((size_t)B * D * 4);
    float* ci_f32 = (float*)alloc((size_t)B * D * 4);
    u16* ri_buf   = (u16*)alloc((size_t)B * D * 2);
    u16* misa_buf = (u16*)alloc((size_t)B * D * 2);
    u16* minfo_buf= (u16*)alloc((size_t)B * D * 2);
    float* gate_b = (float*)alloc((size_t)B * 4);

    // Batch-chunked read path: 3 chunk buffers (bf16 K chunk + 2 ping-pong).
    int chunk_b = 256;
    while (chunk_b > 32) {
        size_t need = off + 3 * (((size_t)chunk_b * HW * D * 2 + 255) & ~(size_t)255);
        if (need <= ws_size) break;
        chunk_b >>= 1;
    }
    u16* kbf  = (u16*)alloc((size_t)chunk_b * HW * D * 2); // bf16(K chunk)
    u16* big1 = (u16*)alloc((size_t)chunk_b * HW * D * 2); // Ii, then rai
    u16* big2 = (u16*)alloc((size_t)chunk_b * HW * D * 2); // X

    dim3 tb(32, 8);
    transpose_k<<<dim3(D / 32, D / 32), tb, 0, stream>>>(W_cq,   wt_cq,  D,     D, D,     0);
    transpose_k<<<dim3(2 * D / 32, D / 32), tb, 0, stream>>>(W_cqi, wt_cqi, 2 * D, D, 2 * D, 0);
    transpose_k<<<dim3(D / 32, D / 32), tb, 0, stream>>>(W_rm,   wt_rm,  D,     D, D,     0);
    transpose_k<<<dim3(D / 32, D / 32), tb, 0, stream>>>(W_rk,   wt_rk,  D,     D, D,     0);
    transpose_k<<<dim3(2 * D / 32, D / 32), tb, 0, stream>>>(W_rik, wt_rik, 2 * D, D, 2 * D, 0);
    transpose_k<<<dim3(D / 32, D / 32), tb, 0, stream>>>(W_rci,  wt_rci, D,     D, D,     0);
    transpose_k<<<dim3(2 * D / 32, D / 32), tb, 0, stream>>>(W_wrm, wt_wrm, 2 * D, D, 2 * D, 0);
    transpose_k<<<dim3(D / 32, D / 32), tb, 0, stream>>>(W_wsa,  wt_wsi, D,     D, 2 * D, 0);
    transpose_k<<<dim3(D / 32, D / 32), tb, 0, stream>>>(W_winfo,wt_wsi, D,     D, 2 * D, D);

    int nbd = B * D;
    conv_f32_bf16<<<nbd / 1024, 256, 0, stream>>>(q, qb, nbd);
    conv_f32_bf16<<<nbd / 1024, 256, 0, stream>>>(ci_1, cib, nbd);
    conv_f32_bf16<<<nbd / 1024, 256, 0, stream>>>(mi_1, mib, nbd);

    dim3 gsmall(D / BN, B / BM); // (4, 2)

    // qi = q @ W_cq + b_cq
    gemm_mfma<<<gsmall, 256, 0, stream>>>(qb, nullptr, B, D, 0, D, wt_cq, b_cq, nullptr,
                                          0, nullptr, 1, nullptr, nullptr, qi_buf, 0);
    // cqi = [ci_1 | qi] @ W_cqi + b_cqi   (f32 out, feeds control scores)
    gemm_mfma<<<gsmall, 256, 0, stream>>>(cib, qi_buf, B, D, D, D, wt_cqi, b_cqi, nullptr,
                                          0, nullptr, 1, nullptr, nullptr, cqi_f32, 1);
    // ci (control attention, all f32)
    control_attn<<<B, 256, 0, stream>>>(cqi_f32, cws, W_cai, b_cai, ci_f32, out_ci);
    // rm = mi_1 @ W_rm + b_rm   (f32 out, epilogue scale)
    gemm_mfma<<<gsmall, 256, 0, stream>>>(mib, nullptr, B, D, 0, D, wt_rm, b_rm, nullptr,
                                          0, nullptr, 1, nullptr, nullptr, rm_f32, 1);

    // read path, chunked over batches
    for (int c = 0; c < B; c += chunk_b) {
        int mrows = chunk_b * HW;
        const float* Kc = Kin + (size_t)c * HW * D;
        conv_f32_bf16<<<(mrows * D) / 1024, 256, 0, stream>>>(Kc, kbf, mrows * D);
        dim3 gbig(D / BN, (mrows + BM - 1) / BM);
        // Ii = (K @ W_rk + b_rk) * rm[b]
        gemm_mfma<<<gbig, 256, 0, stream>>>(kbf, nullptr, mrows, D, 0, D, wt_rk, b_rk, nullptr,
                                            1, rm_f32 + (size_t)c * D, HW, nullptr, nullptr,
                                            big1, 0);
        // X = ([Ii | K] @ W_rik + b_rik) * ci[b]
        gemm_mfma<<<gbig, 256, 0, stream>>>(big1, kbf, mrows, D, D, D, wt_rik, b_rik, nullptr,
                                            1, ci_f32 + (size_t)c * D, HW, nullptr, nullptr,
                                            big2, 0);
        // rai = X @ W_rci + b_rci
        gemm_mfma<<<gbig, 256, 0, stream>>>(big2, nullptr, mrows, D, 0, D, wt_rci, b_rci, nullptr,
                                            0, nullptr, 1, nullptr, nullptr, big1, 0);
        // ri (double softmax over H then W, dot with f32 K)
        read_reduce<<<chunk_b * 2, 256, 0, stream>>>(big1, Kc, ri_buf + (size_t)c * D);
    }

    // mi_info = [ri | mi_1] @ W_wrm + b_wrm
    gemm_mfma<<<gsmall, 256, 0, stream>>>(ri_buf, mib, B, D, D, D, wt_wrm, b_wrm, nullptr,
                                          0, nullptr, 1, nullptr, nullptr, minfo_buf, 0);
    // mi_sa + gate (all f32 math)
    write_attn<<<B, 256, 0, stream>>>(ci_f32, C_past, M_past, W_wcc, b_wcc, W_wci, b_wci,
                                      misa_buf, gate_b);
    // mi = gate*mi_1 + (1-gate)*([mi_sa | mi_info] @ [W_wsa;W_winfo] + b_wsa + b_winfo)
    gemm_mfma<<<gsmall, 256, 0, stream>>>(misa_buf, minfo_buf, B, D, D, D, wt_wsi,
                                          b_wsa, b_winfo, 2, nullptr, 1, gate_b, mi_1,
                                          out_mi, 1);
}

// Round 4
// 775.757 us; speedup vs baseline: 1.0563x; 1.0563x over previous
//
#include <hip/hip_runtime.h>
#include <hip/hip_bf16.h>

typedef unsigned short u16;
typedef __attribute__((ext_vector_type(8))) short short8;
typedef __attribute__((ext_vector_type(4))) float f4;

static __device__ __forceinline__ float b2f(u16 u) {
    union { unsigned int i; float f; } x; x.i = ((unsigned int)u) << 16; return x.f;
}
static __device__ __forceinline__ u16 f2b(float f) {
    union { float f; unsigned int i; } x; x.f = f;
    unsigned int r = x.i + 0x7fffu + ((x.i >> 16) & 1u);
    return (u16)(r >> 16);
}
static __device__ __forceinline__ float wave_reduce_sum(float v) {
    #pragma unroll
    for (int off = 32; off > 0; off >>= 1) v += __shfl_down(v, off, 64);
    return v;
}
// async global->LDS, 16B per lane; lptr must be wave-uniform (lane i lands at lptr + i*16)
static __device__ __forceinline__ void gl2lds(const void* g, void* l) {
    __builtin_amdgcn_global_load_lds(
        (const __attribute__((address_space(1))) void*)g,
        (__attribute__((address_space(3))) void*)l, 16, 0, 0);
}

// ---------------------------------------------------------------- f32 -> bf16 convert
__global__ __launch_bounds__(256) void conv_f32_bf16(
    const float* __restrict__ src, u16* __restrict__ dst, int n)
{
    int i = (blockIdx.x * 256 + threadIdx.x) * 4;
    if (i >= n) return;
    float4 v = *(const float4*)(src + i);
    union { u16 u[4]; uint2 d; } o;
    o.u[0] = f2b(v.x); o.u[1] = f2b(v.y); o.u[2] = f2b(v.z); o.u[3] = f2b(v.w);
    *(uint2*)(dst + i) = o.d;
}

// ---------------------------------------------------------------- transpose f32 -> bf16
// out[n*out_stride + k_off + k] = bf16(in[k*N + n])
__global__ __launch_bounds__(256) void transpose_k(
    const float* __restrict__ in, u16* __restrict__ out,
    int K, int N, int out_stride, int k_off)
{
    __shared__ float t[32][33];
    int kb = blockIdx.x * 32, nb = blockIdx.y * 32;
    int tx = threadIdx.x, ty = threadIdx.y; // blockDim (32,8)
    #pragma unroll
    for (int i = 0; i < 4; i++)
        t[ty + i * 8][tx] = in[(size_t)(kb + ty + i * 8) * N + nb + tx];
    __syncthreads();
    #pragma unroll
    for (int i = 0; i < 4; i++)
        out[(size_t)(nb + ty + i * 8) * out_stride + k_off + kb + tx] =
            f2b(t[tx][ty + i * 8]);
}

// ---------------------------------------------------------------- MFMA GEMM
// C[m,n] = sum_k A0[m,0:K0]*Bt[n,0:K0] + A1[m,0:K1]*Bt[n,K0:K0+K1] + bias (f32)
// epi 0: none; 1: C *= E[(m/m_div), n]; 2: C = g[m]*mi1[m,n] + (1-g[m])*C
// All launches have M % 128 == 0, K0/K1 % 32 == 0, N % 128 == 0.
#define BM 128
#define BN 128
#define BKT 32

__global__ __launch_bounds__(256) void gemm_mfma(
    const u16* __restrict__ A0, const u16* __restrict__ A1,
    int M, int K0, int K1, int N,
    const u16* __restrict__ Bt,
    const float* __restrict__ bias0, const float* __restrict__ bias1,
    int epi_mode, const float* __restrict__ E, int m_div,
    const float* __restrict__ gate, const float* __restrict__ mi1,
    void* __restrict__ Cout, int out_f32)
{
    __shared__ __align__(16) short As[BM * BKT];
    __shared__ __align__(16) short Bs[BN * BKT];
    int tid  = threadIdx.x;
    int wave = tid >> 6, lane = tid & 63;
    int wm = wave >> 1, wn = wave & 1;
    int lrow = lane & 15, quad = lane >> 4;

    // XCD-stripe swizzle: give each XCD a contiguous y-stripe so the gx
    // sibling N-blocks of one M-row-block are co-resident on one XCD's L2.
    int gx = gridDim.x, gy = gridDim.y;
    int bx = blockIdx.x, by = blockIdx.y;
    if ((gy & 7) == 0) {
        int lin = by * gx + bx;
        int xcd = lin & 7, j = lin >> 3;
        by = xcd * (gy >> 3) + j / gx;
        bx = j % gx;
    }
    int bm0 = by * BM, bn0 = bx * BN;
    int Ktot = K0 + K1;

    // staging geometry: wave w deposits rows [32w, 32w+32) of As and Bs,
    // two 1KB wave-loads each (16 rows x 64B). lane -> (row, 16B chunk).
    int r0 = wave * 32;
    int lrow16 = lane >> 2;   // 0..15
    int lchunk = lane & 3;    // 0..3

    f4 acc[4][4];
    #pragma unroll
    for (int i = 0; i < 4; i++)
        #pragma unroll
        for (int j = 0; j < 4; j++)
            acc[i][j] = (f4){0.f, 0.f, 0.f, 0.f};

    for (int k0 = 0; k0 < Ktot; k0 += BKT) {
        const u16* asrc; size_t lda;
        if (k0 < K0) { asrc = A0 + k0;        lda = K0; }
        else         { asrc = A1 + (k0 - K0); lda = K1; }
        const u16* ga0 = asrc + (size_t)(bm0 + r0 + lrow16) * lda + lchunk * 8;
        const u16* gb0 = Bt + (size_t)(bn0 + r0 + lrow16) * Ktot + k0 + lchunk * 8;
        gl2lds(ga0, &As[r0 * BKT]);
        gl2lds(ga0 + 16 * lda, &As[(r0 + 16) * BKT]);
        gl2lds(gb0, &Bs[r0 * BKT]);
        gl2lds(gb0 + 16 * (size_t)Ktot, &Bs[(r0 + 16) * BKT]);
        __syncthreads();   // drains vmcnt (global_load_lds) before ds_read

        short8 af[4], bfr[4];
        #pragma unroll
        for (int mt = 0; mt < 4; mt++)
            af[mt] = *(const short8*)&As[(wm * 64 + mt * 16 + lrow) * BKT + quad * 8];
        #pragma unroll
        for (int nt = 0; nt < 4; nt++)
            bfr[nt] = *(const short8*)&Bs[(wn * 64 + nt * 16 + lrow) * BKT + quad * 8];
        #pragma unroll
        for (int mt = 0; mt < 4; mt++)
            #pragma unroll
            for (int nt = 0; nt < 4; nt++)
                acc[mt][nt] = __builtin_amdgcn_mfma_f32_16x16x32_bf16(
                    af[mt], bfr[nt], acc[mt][nt], 0, 0, 0);
        __syncthreads();
    }

    #pragma unroll
    for (int nt = 0; nt < 4; nt++) {
        int n = bn0 + wn * 64 + nt * 16 + lrow;
        float bv = 0.f;
        if (bias0) bv += bias0[n];
        if (bias1) bv += bias1[n];
        #pragma unroll
        for (int mt = 0; mt < 4; mt++) {
            #pragma unroll
            for (int r = 0; r < 4; r++) {
                int m = bm0 + wm * 64 + mt * 16 + quad * 4 + r;
                float v = acc[mt][nt][r] + bv;
                if (epi_mode == 1) {
                    v *= E[(size_t)(m / m_div) * N + n];
                } else if (epi_mode == 2) {
                    float g = gate[m];
                    v = g * mi1[(size_t)m * N + n] + (1.f - g) * v;
                }
                if (out_f32) ((float*)Cout)[(size_t)m * N + n] = v;
                else         ((u16*)Cout)[(size_t)m * N + n] = f2b(v);
            }
        }
    }
}

// ---------------------------------------------------------------- control attention
// per b: cai[s] = sum_d cqi[b,d]*cws[b,s,d]*Wcai[d] + bcai; softmax_s; ci = sum_s p*cws
__global__ __launch_bounds__(256) void control_attn(
    const float* __restrict__ cqi, const float* __restrict__ cws,
    const float* __restrict__ Wcai, const float* __restrict__ bcai,
    float* __restrict__ ci_f32, float* __restrict__ ci_out)
{
    int b = blockIdx.x, tid = threadIdx.x;
    __shared__ float tW[512];
    __shared__ float p[128];
    __shared__ float inv_l;
    for (int d = tid; d < 512; d += 256)
        tW[d] = cqi[(size_t)b * 512 + d] * Wcai[d];
    __syncthreads();
    int wave = tid >> 6, lane = tid & 63;
    const float* cwsb = cws + (size_t)b * 128 * 512;
    for (int s = wave; s < 128; s += 4) {
        const float* row = cwsb + (size_t)s * 512 + lane * 8;
        float acc = 0.f;
        #pragma unroll
        for (int j = 0; j < 8; j++) acc += tW[lane * 8 + j] * row[j];
        acc = wave_reduce_sum(acc);
        if (lane == 0) p[s] = acc + bcai[0];
    }
    __syncthreads();
    if (tid == 0) {
        float m = -1e30f;
        for (int s = 0; s < 128; s++) m = fmaxf(m, p[s]);
        float l = 0.f;
        for (int s = 0; s < 128; s++) { float e = __expf(p[s] - m); p[s] = e; l += e; }
        inv_l = 1.f / l;
    }
    __syncthreads();
    float inv = inv_l;
    for (int d = tid; d < 512; d += 256) {
        float acc = 0.f;
        for (int s = 0; s < 128; s++) acc += p[s] * cwsb[(size_t)s * 512 + d];
        acc *= inv;
        ci_f32[(size_t)b * 512 + d] = acc;
        ci_out[(size_t)b * 512 + d] = acc;
    }
}

// ---------------------------------------------------------------- read reduce
// per (b,d): softmax over H of rai, then softmax over W of those probs, dot with K
__global__ __launch_bounds__(256) void read_reduce(
    const u16* __restrict__ rai, const float* __restrict__ Kin, u16* __restrict__ ri)
{
    int b = blockIdx.x >> 1;
    int d = ((blockIdx.x & 1) << 8) + threadIdx.x;
    const u16* rb = rai + (size_t)b * 196 * 512 + d;
    const float* kb = Kin + (size_t)b * 196 * 512 + d;
    float m1[14], il1[14];
    #pragma unroll
    for (int w = 0; w < 14; w++) {
        float mm = -1e30f;
        #pragma unroll
        for (int h = 0; h < 14; h++) mm = fmaxf(mm, b2f(rb[(size_t)(h * 14 + w) * 512]));
        float ss = 0.f;
        #pragma unroll
        for (int h = 0; h < 14; h++) ss += __expf(b2f(rb[(size_t)(h * 14 + w) * 512]) - mm);
        m1[w] = mm; il1[w] = 1.f / ss;
    }
    // softmax over W of the H-probabilities, fused with the weighted K-dot
    float acc = 0.f;
    #pragma unroll
    for (int h = 0; h < 14; h++) {
        float pv[14], ss = 0.f;
        #pragma unroll
        for (int w = 0; w < 14; w++) {
            float pr = __expf(b2f(rb[(size_t)(h * 14 + w) * 512]) - m1[w]) * il1[w];
            float e = __expf(pr);
            pv[w] = e; ss += e;
        }
        float il2 = 1.f / ss;
        #pragma unroll
        for (int w = 0; w < 14; w++)
            acc += pv[w] * il2 * kb[(size_t)(h * 14 + w) * 512];
    }
    ri[(size_t)b * 512 + d] = f2b(acc);
}

// ---------------------------------------------------------------- write attention + gate
__global__ __launch_bounds__(256) void write_attn(
    const float* __restrict__ ci_f32, const float* __restrict__ C_past,
    const float* __restrict__ M_past,
    const float* __restrict__ Wwcc, const float* __restrict__ bwcc,
    const float* __restrict__ Wwci, const float* __restrict__ bwci,
    u16* __restrict__ mi_sa, float* __restrict__ gate)
{
    int b = blockIdx.x, tid = threadIdx.x;
    __shared__ float c[512];
    __shared__ float pt[12];
    __shared__ float red[256];
    for (int d = tid; d < 512; d += 256) c[d] = ci_f32[(size_t)b * 512 + d];
    __syncthreads();
    float g = 0.f;
    for (int d = tid; d < 512; d += 256) g += c[d] * Wwci[d];
    red[tid] = g;
    __syncthreads();
    for (int s = 128; s > 0; s >>= 1) {
        if (tid < s) red[tid] += red[tid + s];
        __syncthreads();
    }
    int wave = tid >> 6, lane = tid & 63;
    const float* cp = C_past + (size_t)b * 12 * 512;
    for (int t = wave; t < 12; t += 4) {
        float acc = 0.f;
        #pragma unroll
        for (int j = 0; j < 8; j++) {
            int d = lane * 8 + j;
            acc += c[d] * Wwcc[d] * cp[(size_t)t * 512 + d];
        }
        acc = wave_reduce_sum(acc);
        if (lane == 0) pt[t] = acc + bwcc[0];
    }
    __syncthreads();
    if (tid == 0) {
        float m = -1e30f;
        for (int t = 0; t < 12; t++) m = fmaxf(m, pt[t]);
        float l = 0.f;
        for (int t = 0; t < 12; t++) { float e = __expf(pt[t] - m); pt[t] = e; l += e; }
        float invl = 1.f / l;
        for (int t = 0; t < 12; t++) pt[t] *= invl;
        gate[b] = 1.f / (1.f + __expf(-(red[0] + bwci[0])));
    }
    __syncthreads();
    const float* mp = M_past + (size_t)b * 12 * 512;
    for (int d = tid; d < 512; d += 256) {
        float acc = 0.f;
        #pragma unroll
        for (int t = 0; t < 12; t++) acc += pt[t] * mp[(size_t)t * 512 + d];
        mi_sa[(size_t)b * 512 + d] = f2b(acc);
    }
}

// ---------------------------------------------------------------- launch
extern "C" void kernel_launch(void* const* d_in, const int* in_sizes, int n_in,
                              void* d_out, int out_size, void* d_ws, size_t ws_size,
                              hipStream_t stream) {
    (void)in_sizes; (void)n_in; (void)out_size;
    const int B = 256, D = 512, HW = 196;

    const float* ci_1   = (const float*)d_in[0];
    const float* mi_1   = (const float*)d_in[1];
    const float* q      = (const float*)d_in[2];
    const float* cws    = (const float*)d_in[3];
    const float* Kin    = (const float*)d_in[4];
    const float* C_past = (const float*)d_in[5];
    const float* M_past = (const float*)d_in[6];
    const float* W_cq   = (const float*)d_in[7];
    const float* b_cq   = (const float*)d_in[8];
    const float* W_cqi  = (const float*)d_in[9];
    const float* b_cqi  = (const float*)d_in[10];
    const float* W_cai  = (const float*)d_in[11];
    const float* b_cai  = (const float*)d_in[12];
    const float* W_rm   = (const float*)d_in[13];
    const float* b_rm   = (const float*)d_in[14];
    const float* W_rk   = (const float*)d_in[15];
    const float* b_rk   = (const float*)d_in[16];
    const float* W_rik  = (const float*)d_in[17];
    const float* b_rik  = (const float*)d_in[18];
    const float* W_rci  = (const float*)d_in[19];
    const float* b_rci  = (const float*)d_in[20];
    const float* W_wrm  = (const float*)d_in[21];
    const float* b_wrm  = (const float*)d_in[22];
    const float* W_wcc  = (const float*)d_in[23];
    const float* b_wcc  = (const float*)d_in[24];
    const float* W_wsa  = (const float*)d_in[25];
    const float* b_wsa  = (const float*)d_in[26];
    const float* W_winfo= (const float*)d_in[27];
    const float* b_winfo= (const float*)d_in[28];
    const float* W_wci  = (const float*)d_in[29];
    const float* b_wci  = (const float*)d_in[30];

    float* out_ci = (float*)d_out;
    float* out_mi = (float*)d_out + (size_t)B * D;

    char* ws = (char*)d_ws;
    size_t off = 0;
    auto alloc = [&](size_t bytes) -> void* {
        void* p = ws + off; off += (bytes + 255) & ~(size_t)255; return p;
    };
    u16* wt_cq    = (u16*)alloc((size_t)D * D * 2);
    u16* wt_cqi   = (u16*)alloc((size_t)D * 2 * D * 2);
    u16* wt_rm    = (u16*)alloc((size_t)D * D * 2);
    u16* wt_rk    = (u16*)alloc((size_t)D * D * 2);
    u16* wt_rik   = (u16*)alloc((size_t)D * 2 * D * 2);
    u16* wt_rci   = (u16*)alloc((size_t)D * D * 2);
    u16* wt_wrm   = (u16*)alloc((size_t)D * 2 * D * 2);
    u16* wt_wsi   = (u16*)alloc((size_t)D * 2 * D * 2);
    u16* qb       = (u16*)alloc((size_t)B * D * 2);   // bf16(q)
    u16* cib      = (u16*)alloc((size_t)B * D * 2);   // bf16(ci_1)
    u16* mib      = (u16*)alloc((size_t)B * D * 2);   // bf16(mi_1)
    u16* qi_buf   = (u16*)alloc((size_t)B * D * 2);
    float* cqi_f32= (float*)alloc((size_t)B * D * 4);
    float* rm_f32 = (float*)alloc((size_t)B * D * 4);
    float* ci_f32 = (float*)alloc((size_t)B * D * 4);
    u16* ri_buf   = (u16*)alloc((size_t)B * D * 2);
    u16* misa_buf = (u16*)alloc((size_t)B * D * 2);
    u16* minfo_buf= (u16*)alloc((size_t)B * D * 2);
    float* gate_b = (float*)alloc((size_t)B * 4);

    // Batch-chunked read path: 3 chunk buffers (bf16 K chunk + 2 ping-pong).
    int chunk_b = 256;
    while (chunk_b > 32) {
        size_t need = off + 3 * (((size_t)chunk_b * HW * D * 2 + 255) & ~(size_t)255);
        if (need <= ws_size) break;
        chunk_b >>= 1;
    }
    u16* kbf  = (u16*)alloc((size_t)chunk_b * HW * D * 2); // bf16(K chunk)
    u16* big1 = (u16*)alloc((size_t)chunk_b * HW * D * 2); // Ii, then rai
    u16* big2 = (u16*)alloc((size_t)chunk_b * HW * D * 2); // X

    dim3 tb(32, 8);
    transpose_k<<<dim3(D / 32, D / 32), tb, 0, stream>>>(W_cq,   wt_cq,  D,     D, D,     0);
    transpose_k<<<dim3(2 * D / 32, D / 32), tb, 0, stream>>>(W_cqi, wt_cqi, 2 * D, D, 2 * D, 0);
    transpose_k<<<dim3(D / 32, D / 32), tb, 0, stream>>>(W_rm,   wt_rm,  D,     D, D,     0);
    transpose_k<<<dim3(D / 32, D / 32), tb, 0, stream>>>(W_rk,   wt_rk,  D,     D, D,     0);
    transpose_k<<<dim3(2 * D / 32, D / 32), tb, 0, stream>>>(W_rik, wt_rik, 2 * D, D, 2 * D, 0);
    transpose_k<<<dim3(D / 32, D / 32), tb, 0, stream>>>(W_rci,  wt_rci, D,     D, D,     0);
    transpose_k<<<dim3(2 * D / 32, D / 32), tb, 0, stream>>>(W_wrm, wt_wrm, 2 * D, D, 2 * D, 0);
    transpose_k<<<dim3(D / 32, D / 32), tb, 0, stream>>>(W_wsa,  wt_wsi, D,     D, 2 * D, 0);
    transpose_k<<<dim3(D / 32, D / 32), tb, 0, stream>>>(W_winfo,wt_wsi, D,     D, 2 * D, D);

    int nbd = B * D;
    conv_f32_bf16<<<nbd / 1024, 256, 0, stream>>>(q, qb, nbd);
    conv_f32_bf16<<<nbd / 1024, 256, 0, stream>>>(ci_1, cib, nbd);
    conv_f32_bf16<<<nbd / 1024, 256, 0, stream>>>(mi_1, mib, nbd);

    dim3 gsmall(D / BN, B / BM); // (4, 2)

    // qi = q @ W_cq + b_cq
    gemm_mfma<<<gsmall, 256, 0, stream>>>(qb, nullptr, B, D, 0, D, wt_cq, b_cq, nullptr,
                                          0, nullptr, 1, nullptr, nullptr, qi_buf, 0);
    // cqi = [ci_1 | qi] @ W_cqi + b_cqi   (f32 out, feeds control scores)
    gemm_mfma<<<gsmall, 256, 0, stream>>>(cib, qi_buf, B, D, D, D, wt_cqi, b_cqi, nullptr,
                                          0, nullptr, 1, nullptr, nullptr, cqi_f32, 1);
    // ci (control attention, all f32)
    control_attn<<<B, 256, 0, stream>>>(cqi_f32, cws, W_cai, b_cai, ci_f32, out_ci);
    // rm = mi_1 @ W_rm + b_rm   (f32 out, epilogue scale)
    gemm_mfma<<<gsmall, 256, 0, stream>>>(mib, nullptr, B, D, 0, D, wt_rm, b_rm, nullptr,
                                          0, nullptr, 1, nullptr, nullptr, rm_f32, 1);

    // read path, chunked over batches
    for (int c = 0; c < B; c += chunk_b) {
        int mrows = chunk_b * HW;
        const float* Kc = Kin + (size_t)c * HW * D;
        conv_f32_bf16<<<(mrows * D) / 1024, 256, 0, stream>>>(Kc, kbf, mrows * D);
        dim3 gbig(D / BN, mrows / BM);
        // Ii = (K @ W_rk + b_rk) * rm[b]
        gemm_mfma<<<gbig, 256, 0, stream>>>(kbf, nullptr, mrows, D, 0, D, wt_rk, b_rk, nullptr,
                                            1, rm_f32 + (size_t)c * D, HW, nullptr, nullptr,
                                            big1, 0);
        // X = ([Ii | K] @ W_rik + b_rik) * ci[b]
        gemm_mfma<<<gbig, 256, 0, stream>>>(big1, kbf, mrows, D, D, D, wt_rik, b_rik, nullptr,
                                            1, ci_f32 + (size_t)c * D, HW, nullptr, nullptr,
                                            big2, 0);
        // rai = X @ W_rci + b_rci
        gemm_mfma<<<gbig, 256, 0, stream>>>(big2, nullptr, mrows, D, 0, D, wt_rci, b_rci, nullptr,
                                            0, nullptr, 1, nullptr, nullptr, big1, 0);
        // ri (double softmax over H then W, dot with f32 K)
        read_reduce<<<chunk_b * 2, 256, 0, stream>>>(big1, Kc, ri_buf + (size_t)c * D);
    }

    // mi_info = [ri | mi_1] @ W_wrm + b_wrm
    gemm_mfma<<<gsmall, 256, 0, stream>>>(ri_buf, mib, B, D, D, D, wt_wrm, b_wrm, nullptr,
                                          0, nullptr, 1, nullptr, nullptr, minfo_buf, 0);
    // mi_sa + gate (all f32 math)
    write_attn<<<B, 256, 0, stream>>>(ci_f32, C_past, M_past, W_wcc, b_wcc, W_wci, b_wci,
                                      misa_buf, gate_b);
    // mi = gate*mi_1 + (1-gate)*([mi_sa | mi_info] @ [W_wsa;W_winfo] + b_wsa + b_winfo)
    gemm_mfma<<<gsmall, 256, 0, stream>>>(misa_buf, minfo_buf, B, D, D, D, wt_wsi,
                                          b_wsa, b_winfo, 2, nullptr, 1, gate_b, mi_1,
                                          out_mi, 1);
}

// Round 5
// 678.460 us; speedup vs baseline: 1.2078x; 1.1434x over previous
//
#include <hip/hip_runtime.h>
#include <hip/hip_bf16.h>

typedef unsigned short u16;
typedef __attribute__((ext_vector_type(8))) short short8;
typedef __attribute__((ext_vector_type(4))) float f4;

static __device__ __forceinline__ float b2f(u16 u) {
    union { unsigned int i; float f; } x; x.i = ((unsigned int)u) << 16; return x.f;
}
static __device__ __forceinline__ u16 f2b(float f) {
    union { float f; unsigned int i; } x; x.f = f;
    unsigned int r = x.i + 0x7fffu + ((x.i >> 16) & 1u);
    return (u16)(r >> 16);
}
static __device__ __forceinline__ float wave_reduce_sum(float v) {
    #pragma unroll
    for (int off = 32; off > 0; off >>= 1) v += __shfl_down(v, off, 64);
    return v;
}
// async global->LDS, 16B per lane; lane i lands at ldsbase + i*16
static __device__ __forceinline__ void gl2lds(const void* g, void* l) {
    __builtin_amdgcn_global_load_lds(
        (const __attribute__((address_space(1))) void*)g,
        (__attribute__((address_space(3))) void*)l, 16, 0, 0);
}

// ---------------------------------------------------------------- f32 -> bf16 convert
__global__ __launch_bounds__(256) void conv_f32_bf16(
    const float* __restrict__ src, u16* __restrict__ dst, int n)
{
    int i = (blockIdx.x * 256 + threadIdx.x) * 4;
    if (i >= n) return;
    float4 v = *(const float4*)(src + i);
    union { u16 u[4]; uint2 d; } o;
    o.u[0] = f2b(v.x); o.u[1] = f2b(v.y); o.u[2] = f2b(v.z); o.u[3] = f2b(v.w);
    *(uint2*)(dst + i) = o.d;
}

// ---------------------------------------------------------------- transpose f32 -> bf16
__global__ __launch_bounds__(256) void transpose_k(
    const float* __restrict__ in, u16* __restrict__ out,
    int K, int N, int out_stride, int k_off)
{
    __shared__ float t[32][33];
    int kb = blockIdx.x * 32, nb = blockIdx.y * 32;
    int tx = threadIdx.x, ty = threadIdx.y; // blockDim (32,8)
    #pragma unroll
    for (int i = 0; i < 4; i++)
        t[ty + i * 8][tx] = in[(size_t)(kb + ty + i * 8) * N + nb + tx];
    __syncthreads();
    #pragma unroll
    for (int i = 0; i < 4; i++)
        out[(size_t)(nb + ty + i * 8) * out_stride + k_off + kb + tx] =
            f2b(t[tx][ty + i * 8]);
}

// ---------------------------------------------------------------- MFMA GEMM (pipelined)
// C[m,n] = sum_k A0[m,0:K0]*Bt[n,0:K0] + A1[m,0:K1]*Bt[n,K0:K0+K1] + bias (f32)
// epi 0: none; 1: C *= E[(m/m_div), n]; 2: C = g[m]*mi1[m,n] + (1-g[m])*C
// M % 128 == 0, K0/K1 % 32 == 0, N % (NT*32) == 0.
template<int NT>   // n-tiles per wave; BN = NT*32 (128 or 256)
__global__ __launch_bounds__(256) void gemm_mfma(
    const u16* __restrict__ A0, const u16* __restrict__ A1,
    int M, int K0, int K1, int N,
    const u16* __restrict__ Bt,
    const float* __restrict__ bias0, const float* __restrict__ bias1,
    int epi_mode, const float* __restrict__ E, int m_div,
    const float* __restrict__ gate, const float* __restrict__ mi1,
    void* __restrict__ Cout, int out_f32)
{
    constexpr int BN = NT * 32;
    constexpr int STAGE_B = 2 * (128 * 32 + BN * 32) * 2;   // bytes, 2 buffers
    constexpr int EP_B = 32 * 260 * 4;                       // epilogue staging
    __shared__ __align__(16) char smem[STAGE_B > EP_B ? STAGE_B : EP_B];
    short* As  = (short*)smem;               // [2][128*32]
    short* Bsh = (short*)(smem + 2 * 128 * 32 * 2); // [2][BN*32]
    float* ep  = (float*)smem;               // [32][260]

    int tid  = threadIdx.x;
    int wave = tid >> 6, lane = tid & 63;
    int wm = wave >> 1, wn = wave & 1;
    int lrow = lane & 15, quad = lane >> 4;

    // XCD-stripe swizzle (gy % 8 == 0 only)
    int gx = gridDim.x, gy = gridDim.y;
    int bx = blockIdx.x, by = blockIdx.y;
    if ((gy & 7) == 0) {
        int lin = by * gx + bx;
        int xcd = lin & 7, j = lin >> 3;
        by = xcd * (gy >> 3) + j / gx;
        bx = j % gx;
    }
    int bm0 = by * 128, bn0 = bx * BN;
    int Ktot = K0 + K1;
    int KT = Ktot >> 5;

    // staging lane geometry: r16 = row within 16-row group, cc = 16B chunk slot
    int r16 = lane >> 2, cc = lane & 3;
    int sw = (r16 >> 1) & 3;
    int coff = (cc ^ sw) * 8;  // elements; slot cc holds global chunk cc^sw

    auto stage = [&](int bi, int k0) {
        const u16* asrc; int lda;
        if (k0 < K0) { asrc = A0 + k0; lda = K0; }
        else         { asrc = A1 + (k0 - K0); lda = K1; }
        int ar = wave * 32;
        const u16* ga = asrc + (size_t)(bm0 + ar + r16) * lda + coff;
        gl2lds(ga, As + (bi * 128 + ar) * 32);
        gl2lds(ga + (size_t)16 * lda, As + (bi * 128 + ar + 16) * 32);
        int br = wave * (BN / 4);
        const u16* gb = Bt + (size_t)(bn0 + br + r16) * Ktot + k0 + coff;
        #pragma unroll
        for (int i = 0; i < BN / 64; i++)
            gl2lds(gb + (size_t)(16 * i) * Ktot, Bsh + (bi * BN + br + 16 * i) * 32);
    };

    f4 acc[4][NT];
    #pragma unroll
    for (int i = 0; i < 4; i++)
        #pragma unroll
        for (int j = 0; j < NT; j++)
            acc[i][j] = (f4){0.f, 0.f, 0.f, 0.f};

    stage(0, 0);
    int sw2 = (lrow >> 1) & 3;
    for (int kt = 0; kt < KT; kt++) {
        __syncthreads();  // drains vmcnt: buf[kt&1] ready; prev reads done
        const short* Ab = As + (kt & 1) * 128 * 32;
        const short* Bb = Bsh + (kt & 1) * BN * 32;
        short8 af[4], bfr[NT];
        #pragma unroll
        for (int mt = 0; mt < 4; mt++)
            af[mt] = *(const short8*)&Ab[(wm * 64 + mt * 16 + lrow) * 32 + (quad ^ sw2) * 8];
        #pragma unroll
        for (int nt = 0; nt < NT; nt++)
            bfr[nt] = *(const short8*)&Bb[(wn * (NT * 16) + nt * 16 + lrow) * 32 + (quad ^ sw2) * 8];
        if (kt + 1 < KT) stage((kt + 1) & 1, (kt + 1) * 32);  // prefetch under MFMA shadow
        #pragma unroll
        for (int mt = 0; mt < 4; mt++)
            #pragma unroll
            for (int nt = 0; nt < NT; nt++)
                acc[mt][nt] = __builtin_amdgcn_mfma_f32_16x16x32_bf16(
                    af[mt], bfr[nt], acc[mt][nt], 0, 0, 0);
    }

    // -------- coalesced epilogue via LDS (4 passes of 32 rows) --------
    __syncthreads();
    int rr = tid >> 3, c8 = tid & 7;
    #pragma unroll
    for (int p = 0; p < 4; p++) {
        if (wm == (p >> 1)) {
            #pragma unroll
            for (int mh = 0; mh < 2; mh++) {
                int mt = 2 * (p & 1) + mh;
                int lm = mh * 16 + quad * 4;
                #pragma unroll
                for (int nt = 0; nt < NT; nt++) {
                    int col = wn * (NT * 16) + nt * 16 + lrow;
                    #pragma unroll
                    for (int r = 0; r < 4; r++)
                        ep[(lm + r) * 260 + col] = acc[mt][nt][r];
                }
            }
        }
        __syncthreads();
        int m = bm0 + p * 32 + rr;
        #pragma unroll
        for (int i = 0; i < NT; i++) {
            int ci = i * 8 + c8;
            int n = bn0 + ci * 4;
            float4 v = *(const float4*)&ep[rr * 260 + ci * 4];
            if (bias0) {
                float4 bb = *(const float4*)&bias0[n];
                v.x += bb.x; v.y += bb.y; v.z += bb.z; v.w += bb.w;
            }
            if (bias1) {
                float4 bb = *(const float4*)&bias1[n];
                v.x += bb.x; v.y += bb.y; v.z += bb.z; v.w += bb.w;
            }
            if (epi_mode == 1) {
                const float* Er = E + (size_t)(m / m_div) * N + n;
                float4 e = *(const float4*)Er;
                v.x *= e.x; v.y *= e.y; v.z *= e.z; v.w *= e.w;
            } else if (epi_mode == 2) {
                float g = gate[m];
                const float* mr = mi1 + (size_t)m * N + n;
                float4 mm = *(const float4*)mr;
                v.x = g * mm.x + (1.f - g) * v.x;
                v.y = g * mm.y + (1.f - g) * v.y;
                v.z = g * mm.z + (1.f - g) * v.z;
                v.w = g * mm.w + (1.f - g) * v.w;
            }
            if (out_f32) {
                *(float4*)((float*)Cout + (size_t)m * N + n) = v;
            } else {
                union { u16 u[4]; uint2 d; } o;
                o.u[0] = f2b(v.x); o.u[1] = f2b(v.y);
                o.u[2] = f2b(v.z); o.u[3] = f2b(v.w);
                *(uint2*)((u16*)Cout + (size_t)m * N + n) = o.d;
            }
        }
        __syncthreads();
    }
}

// ---------------------------------------------------------------- control attention
__global__ __launch_bounds__(256) void control_attn(
    const float* __restrict__ cqi, const float* __restrict__ cws,
    const float* __restrict__ Wcai, const float* __restrict__ bcai,
    float* __restrict__ ci_f32, float* __restrict__ ci_out)
{
    int b = blockIdx.x, tid = threadIdx.x;
    __shared__ float tW[512];
    __shared__ float p[128];
    __shared__ float inv_l;
    for (int d = tid; d < 512; d += 256)
        tW[d] = cqi[(size_t)b * 512 + d] * Wcai[d];
    __syncthreads();
    int wave = tid >> 6, lane = tid & 63;
    const float* cwsb = cws + (size_t)b * 128 * 512;
    for (int s = wave; s < 128; s += 4) {
        const float* row = cwsb + (size_t)s * 512 + lane * 8;
        float acc = 0.f;
        #pragma unroll
        for (int j = 0; j < 8; j++) acc += tW[lane * 8 + j] * row[j];
        acc = wave_reduce_sum(acc);
        if (lane == 0) p[s] = acc + bcai[0];
    }
    __syncthreads();
    if (tid == 0) {
        float m = -1e30f;
        for (int s = 0; s < 128; s++) m = fmaxf(m, p[s]);
        float l = 0.f;
        for (int s = 0; s < 128; s++) { float e = __expf(p[s] - m); p[s] = e; l += e; }
        inv_l = 1.f / l;
    }
    __syncthreads();
    float inv = inv_l;
    for (int d = tid; d < 512; d += 256) {
        float acc = 0.f;
        for (int s = 0; s < 128; s++) acc += p[s] * cwsb[(size_t)s * 512 + d];
        acc *= inv;
        ci_f32[(size_t)b * 512 + d] = acc;
        ci_out[(size_t)b * 512 + d] = acc;
    }
}

// ---------------------------------------------------------------- read reduce
__global__ __launch_bounds__(256) void read_reduce(
    const u16* __restrict__ rai, const float* __restrict__ Kin, u16* __restrict__ ri)
{
    int b = blockIdx.x >> 1;
    int d = ((blockIdx.x & 1) << 8) + threadIdx.x;
    const u16* rb = rai + (size_t)b * 196 * 512 + d;
    const float* kb = Kin + (size_t)b * 196 * 512 + d;
    float m1[14], il1[14];
    #pragma unroll
    for (int w = 0; w < 14; w++) {
        float mm = -1e30f;
        #pragma unroll
        for (int h = 0; h < 14; h++) mm = fmaxf(mm, b2f(rb[(size_t)(h * 14 + w) * 512]));
        float ss = 0.f;
        #pragma unroll
        for (int h = 0; h < 14; h++) ss += __expf(b2f(rb[(size_t)(h * 14 + w) * 512]) - mm);
        m1[w] = mm; il1[w] = 1.f / ss;
    }
    float acc = 0.f;
    #pragma unroll
    for (int h = 0; h < 14; h++) {
        float pv[14], ss = 0.f;
        #pragma unroll
        for (int w = 0; w < 14; w++) {
            float pr = __expf(b2f(rb[(size_t)(h * 14 + w) * 512]) - m1[w]) * il1[w];
            float e = __expf(pr);
            pv[w] = e; ss += e;
        }
        float il2 = 1.f / ss;
        #pragma unroll
        for (int w = 0; w < 14; w++)
            acc += pv[w] * il2 * kb[(size_t)(h * 14 + w) * 512];
    }
    ri[(size_t)b * 512 + d] = f2b(acc);
}

// ---------------------------------------------------------------- write attention + gate
__global__ __launch_bounds__(256) void write_attn(
    const float* __restrict__ ci_f32, const float* __restrict__ C_past,
    const float* __restrict__ M_past,
    const float* __restrict__ Wwcc, const float* __restrict__ bwcc,
    const float* __restrict__ Wwci, const float* __restrict__ bwci,
    u16* __restrict__ mi_sa, float* __restrict__ gate)
{
    int b = blockIdx.x, tid = threadIdx.x;
    __shared__ float c[512];
    __shared__ float pt[12];
    __shared__ float red[256];
    for (int d = tid; d < 512; d += 256) c[d] = ci_f32[(size_t)b * 512 + d];
    __syncthreads();
    float g = 0.f;
    for (int d = tid; d < 512; d += 256) g += c[d] * Wwci[d];
    red[tid] = g;
    __syncthreads();
    for (int s = 128; s > 0; s >>= 1) {
        if (tid < s) red[tid] += red[tid + s];
        __syncthreads();
    }
    int wave = tid >> 6, lane = tid & 63;
    const float* cp = C_past + (size_t)b * 12 * 512;
    for (int t = wave; t < 12; t += 4) {
        float acc = 0.f;
        #pragma unroll
        for (int j = 0; j < 8; j++) {
            int d = lane * 8 + j;
            acc += c[d] * Wwcc[d] * cp[(size_t)t * 512 + d];
        }
        acc = wave_reduce_sum(acc);
        if (lane == 0) pt[t] = acc + bwcc[0];
    }
    __syncthreads();
    if (tid == 0) {
        float m = -1e30f;
        for (int t = 0; t < 12; t++) m = fmaxf(m, pt[t]);
        float l = 0.f;
        for (int t = 0; t < 12; t++) { float e = __expf(pt[t] - m); pt[t] = e; l += e; }
        float invl = 1.f / l;
        for (int t = 0; t < 12; t++) pt[t] *= invl;
        gate[b] = 1.f / (1.f + __expf(-(red[0] + bwci[0])));
    }
    __syncthreads();
    const float* mp = M_past + (size_t)b * 12 * 512;
    for (int d = tid; d < 512; d += 256) {
        float acc = 0.f;
        #pragma unroll
        for (int t = 0; t < 12; t++) acc += pt[t] * mp[(size_t)t * 512 + d];
        mi_sa[(size_t)b * 512 + d] = f2b(acc);
    }
}

// ---------------------------------------------------------------- launch
extern "C" void kernel_launch(void* const* d_in, const int* in_sizes, int n_in,
                              void* d_out, int out_size, void* d_ws, size_t ws_size,
                              hipStream_t stream) {
    (void)in_sizes; (void)n_in; (void)out_size;
    const int B = 256, D = 512, HW = 196;

    const float* ci_1   = (const float*)d_in[0];
    const float* mi_1   = (const float*)d_in[1];
    const float* q      = (const float*)d_in[2];
    const float* cws    = (const float*)d_in[3];
    const float* Kin    = (const float*)d_in[4];
    const float* C_past = (const float*)d_in[5];
    const float* M_past = (const float*)d_in[6];
    const float* W_cq   = (const float*)d_in[7];
    const float* b_cq   = (const float*)d_in[8];
    const float* W_cqi  = (const float*)d_in[9];
    const float* b_cqi  = (const float*)d_in[10];
    const float* W_cai  = (const float*)d_in[11];
    const float* b_cai  = (const float*)d_in[12];
    const float* W_rm   = (const float*)d_in[13];
    const float* b_rm   = (const float*)d_in[14];
    const float* W_rk   = (const float*)d_in[15];
    const float* b_rk   = (const float*)d_in[16];
    const float* W_rik  = (const float*)d_in[17];
    const float* b_rik  = (const float*)d_in[18];
    const float* W_rci  = (const float*)d_in[19];
    const float* b_rci  = (const float*)d_in[20];
    const float* W_wrm  = (const float*)d_in[21];
    const float* b_wrm  = (const float*)d_in[22];
    const float* W_wcc  = (const float*)d_in[23];
    const float* b_wcc  = (const float*)d_in[24];
    const float* W_wsa  = (const float*)d_in[25];
    const float* b_wsa  = (const float*)d_in[26];
    const float* W_winfo= (const float*)d_in[27];
    const float* b_winfo= (const float*)d_in[28];
    const float* W_wci  = (const float*)d_in[29];
    const float* b_wci  = (const float*)d_in[30];

    float* out_ci = (float*)d_out;
    float* out_mi = (float*)d_out + (size_t)B * D;

    char* ws = (char*)d_ws;
    size_t off = 0;
    auto alloc = [&](size_t bytes) -> void* {
        void* p = ws + off; off += (bytes + 255) & ~(size_t)255; return p;
    };
    u16* wt_cq    = (u16*)alloc((size_t)D * D * 2);
    u16* wt_cqi   = (u16*)alloc((size_t)D * 2 * D * 2);
    u16* wt_rm    = (u16*)alloc((size_t)D * D * 2);
    u16* wt_rk    = (u16*)alloc((size_t)D * D * 2);
    u16* wt_rik   = (u16*)alloc((size_t)D * 2 * D * 2);
    u16* wt_rci   = (u16*)alloc((size_t)D * D * 2);
    u16* wt_wrm   = (u16*)alloc((size_t)D * 2 * D * 2);
    u16* wt_wsi   = (u16*)alloc((size_t)D * 2 * D * 2);
    u16* qb       = (u16*)alloc((size_t)B * D * 2);
    u16* cib      = (u16*)alloc((size_t)B * D * 2);
    u16* mib      = (u16*)alloc((size_t)B * D * 2);
    u16* qi_buf   = (u16*)alloc((size_t)B * D * 2);
    float* cqi_f32= (float*)alloc((size_t)B * D * 4);
    float* rm_f32 = (float*)alloc((size_t)B * D * 4);
    float* ci_f32 = (float*)alloc((size_t)B * D * 4);
    u16* ri_buf   = (u16*)alloc((size_t)B * D * 2);
    u16* misa_buf = (u16*)alloc((size_t)B * D * 2);
    u16* minfo_buf= (u16*)alloc((size_t)B * D * 2);
    float* gate_b = (float*)alloc((size_t)B * 4);

    int chunk_b = 256;
    while (chunk_b > 32) {
        size_t need = off + 3 * (((size_t)chunk_b * HW * D * 2 + 255) & ~(size_t)255);
        if (need <= ws_size) break;
        chunk_b >>= 1;
    }
    u16* kbf  = (u16*)alloc((size_t)chunk_b * HW * D * 2);
    u16* big1 = (u16*)alloc((size_t)chunk_b * HW * D * 2);
    u16* big2 = (u16*)alloc((size_t)chunk_b * HW * D * 2);

    dim3 tb(32, 8);
    transpose_k<<<dim3(D / 32, D / 32), tb, 0, stream>>>(W_cq,   wt_cq,  D,     D, D,     0);
    transpose_k<<<dim3(2 * D / 32, D / 32), tb, 0, stream>>>(W_cqi, wt_cqi, 2 * D, D, 2 * D, 0);
    transpose_k<<<dim3(D / 32, D / 32), tb, 0, stream>>>(W_rm,   wt_rm,  D,     D, D,     0);
    transpose_k<<<dim3(D / 32, D / 32), tb, 0, stream>>>(W_rk,   wt_rk,  D,     D, D,     0);
    transpose_k<<<dim3(2 * D / 32, D / 32), tb, 0, stream>>>(W_rik, wt_rik, 2 * D, D, 2 * D, 0);
    transpose_k<<<dim3(D / 32, D / 32), tb, 0, stream>>>(W_rci,  wt_rci, D,     D, D,     0);
    transpose_k<<<dim3(2 * D / 32, D / 32), tb, 0, stream>>>(W_wrm, wt_wrm, 2 * D, D, 2 * D, 0);
    transpose_k<<<dim3(D / 32, D / 32), tb, 0, stream>>>(W_wsa,  wt_wsi, D,     D, 2 * D, 0);
    transpose_k<<<dim3(D / 32, D / 32), tb, 0, stream>>>(W_winfo,wt_wsi, D,     D, 2 * D, D);

    int nbd = B * D;
    conv_f32_bf16<<<nbd / 1024, 256, 0, stream>>>(q, qb, nbd);
    conv_f32_bf16<<<nbd / 1024, 256, 0, stream>>>(ci_1, cib, nbd);
    conv_f32_bf16<<<nbd / 1024, 256, 0, stream>>>(mi_1, mib, nbd);

    dim3 gsmall(D / 128, B / 128); // (4, 2)

    gemm_mfma<4><<<gsmall, 256, 0, stream>>>(qb, nullptr, B, D, 0, D, wt_cq, b_cq, nullptr,
                                             0, nullptr, 1, nullptr, nullptr, qi_buf, 0);
    gemm_mfma<4><<<gsmall, 256, 0, stream>>>(cib, qi_buf, B, D, D, D, wt_cqi, b_cqi, nullptr,
                                             0, nullptr, 1, nullptr, nullptr, cqi_f32, 1);
    control_attn<<<B, 256, 0, stream>>>(cqi_f32, cws, W_cai, b_cai, ci_f32, out_ci);
    gemm_mfma<4><<<gsmall, 256, 0, stream>>>(mib, nullptr, B, D, 0, D, wt_rm, b_rm, nullptr,
                                             0, nullptr, 1, nullptr, nullptr, rm_f32, 1);

    for (int c = 0; c < B; c += chunk_b) {
        int mrows = chunk_b * HW;
        const float* Kc = Kin + (size_t)c * HW * D;
        conv_f32_bf16<<<(mrows * D) / 1024, 256, 0, stream>>>(Kc, kbf, mrows * D);
        dim3 gbig(D / 256, mrows / 128);
        gemm_mfma<8><<<gbig, 256, 0, stream>>>(kbf, nullptr, mrows, D, 0, D, wt_rk, b_rk, nullptr,
                                               1, rm_f32 + (size_t)c * D, HW, nullptr, nullptr,
                                               big1, 0);
        gemm_mfma<8><<<gbig, 256, 0, stream>>>(big1, kbf, mrows, D, D, D, wt_rik, b_rik, nullptr,
                                               1, ci_f32 + (size_t)c * D, HW, nullptr, nullptr,
                                               big2, 0);
        gemm_mfma<8><<<gbig, 256, 0, stream>>>(big2, nullptr, mrows, D, 0, D, wt_rci, b_rci, nullptr,
                                               0, nullptr, 1, nullptr, nullptr, big1, 0);
        read_reduce<<<chunk_b * 2, 256, 0, stream>>>(big1, Kc, ri_buf + (size_t)c * D);
    }

    gemm_mfma<4><<<gsmall, 256, 0, stream>>>(ri_buf, mib, B, D, D, D, wt_wrm, b_wrm, nullptr,
                                             0, nullptr, 1, nullptr, nullptr, minfo_buf, 0);
    write_attn<<<B, 256, 0, stream>>>(ci_f32, C_past, M_past, W_wcc, b_wcc, W_wci, b_wci,
                                      misa_buf, gate_b);
    gemm_mfma<4><<<gsmall, 256, 0, stream>>>(misa_buf, minfo_buf, B, D, D, D, wt_wsi,
                                             b_wsa, b_winfo, 2, nullptr, 1, gate_b, mi_1,
                                             out_mi, 1);
}

// Round 6
// 614.496 us; speedup vs baseline: 1.3335x; 1.1041x over previous
//
#include <hip/hip_runtime.h>
#include <hip/hip_bf16.h>

typedef unsigned short u16;
typedef __attribute__((ext_vector_type(8))) short short8;
typedef __attribute__((ext_vector_type(4))) float f4;

static __device__ __forceinline__ float b2f(u16 u) {
    union { unsigned int i; float f; } x; x.i = ((unsigned int)u) << 16; return x.f;
}
static __device__ __forceinline__ u16 f2b(float f) {
    union { float f; unsigned int i; } x; x.f = f;
    unsigned int r = x.i + 0x7fffu + ((x.i >> 16) & 1u);
    return (u16)(r >> 16);
}
static __device__ __forceinline__ float wave_reduce_sum(float v) {
    #pragma unroll
    for (int off = 32; off > 0; off >>= 1) v += __shfl_down(v, off, 64);
    return v;
}
// async global->LDS, 16B per lane; lane i lands at ldsbase + i*16
static __device__ __forceinline__ void gl2lds(const void* g, void* l) {
    __builtin_amdgcn_global_load_lds(
        (const __attribute__((address_space(1))) void*)g,
        (__attribute__((address_space(3))) void*)l, 16, 0, 0);
}

// ---------------------------------------------------------------- f32 -> bf16 convert
__global__ __launch_bounds__(256) void conv_f32_bf16(
    const float* __restrict__ src, u16* __restrict__ dst, int n)
{
    int i = (blockIdx.x * 256 + threadIdx.x) * 4;
    if (i >= n) return;
    float4 v = *(const float4*)(src + i);
    union { u16 u[4]; uint2 d; } o;
    o.u[0] = f2b(v.x); o.u[1] = f2b(v.y); o.u[2] = f2b(v.z); o.u[3] = f2b(v.w);
    *(uint2*)(dst + i) = o.d;
}

// ---------------------------------------------------------------- transpose f32 -> bf16
__global__ __launch_bounds__(256) void transpose_k(
    const float* __restrict__ in, u16* __restrict__ out,
    int K, int N, int out_stride, int k_off)
{
    __shared__ float t[32][33];
    int kb = blockIdx.x * 32, nb = blockIdx.y * 32;
    int tx = threadIdx.x, ty = threadIdx.y; // blockDim (32,8)
    #pragma unroll
    for (int i = 0; i < 4; i++)
        t[ty + i * 8][tx] = in[(size_t)(kb + ty + i * 8) * N + nb + tx];
    __syncthreads();
    #pragma unroll
    for (int i = 0; i < 4; i++)
        out[(size_t)(nb + ty + i * 8) * out_stride + k_off + kb + tx] =
            f2b(t[tx][ty + i * 8]);
}

// ---------------------------------------------------------------- MFMA GEMM
// 3-stage LDS pipeline, distance-2 prefetch, raw vmcnt(NPF) barrier (AITER-style).
// C[m,n] = sum_k A0[m,0:K0]*Bt[n,0:K0] + A1[m,0:K1]*Bt[n,K0:K0+K1] + bias (f32)
// epi 0: none; 1: C *= E[(m/m_div), n]; 2: C = g[m]*mi1[m,n] + (1-g[m])*C
// M % (MT*32) == 0, K0/K1 % 32 == 0, N % (NT*32) == 0.
template<int MT, int NT>   // block tile = (MT*32) x (NT*32); 4 waves in 2x2
__global__ __launch_bounds__(256) void gemm_mfma(
    const u16* __restrict__ A0, const u16* __restrict__ A1,
    int M, int K0, int K1, int N,
    const u16* __restrict__ Bt,
    const float* __restrict__ bias0, const float* __restrict__ bias1,
    int epi_mode, const float* __restrict__ E, int m_div,
    const float* __restrict__ gate, const float* __restrict__ mi1,
    void* __restrict__ Cout, int out_f32)
{
    constexpr int BM = MT * 32, BN = NT * 32;
    constexpr int STG = (BM + BN) * 32;          // shorts per stage
    constexpr int NPF = MT / 2 + NT / 2;         // DMA loads per stage per wave
    constexpr int STAGE_B = 3 * STG * 2;
    constexpr int EP_B = (MT == 4) ? 32 * 260 * 4 : 0;
    __shared__ __align__(16) char smem[(STAGE_B > EP_B) ? STAGE_B : EP_B];
    short* stg = (short*)smem;
    float* ep  = (float*)smem;

    int tid  = threadIdx.x;
    int wave = tid >> 6, lane = tid & 63;
    int wm = wave >> 1, wn = wave & 1;
    int lrow = lane & 15, quad = lane >> 4;

    // XCD-stripe swizzle (gy % 8 == 0 only)
    int gx = gridDim.x, gy = gridDim.y;
    int bx = blockIdx.x, by = blockIdx.y;
    if ((gy & 7) == 0) {
        int lin = by * gx + bx;
        int xcd = lin & 7, j = lin >> 3;
        by = xcd * (gy >> 3) + j / gx;
        bx = j % gx;
    }
    int bm0 = by * BM, bn0 = bx * BN;
    int Ktot = K0 + K1;
    int KT = Ktot >> 5;

    // staging lane geometry: 16 rows x 64B per DMA, XOR-swizzled 16B chunks
    int r16 = lane >> 2, cc = lane & 3;
    int sw = (r16 >> 1) & 3;
    int coff = (cc ^ sw) * 8;

    auto stage = [&](int s, int k0) {
        const u16* asrc; int lda;
        if (k0 < K0) { asrc = A0 + k0; lda = K0; }
        else         { asrc = A1 + (k0 - K0); lda = K1; }
        short* As = stg + s * STG;
        short* Bs = As + BM * 32;
        #pragma unroll
        for (int i = 0; i < MT / 2; i++) {
            int ar = wave * (BM / 4) + 16 * i;
            gl2lds(asrc + (size_t)(bm0 + ar + r16) * lda + coff, As + ar * 32);
        }
        #pragma unroll
        for (int i = 0; i < NT / 2; i++) {
            int br = wave * (BN / 4) + 16 * i;
            gl2lds(Bt + (size_t)(bn0 + br + r16) * Ktot + k0 + coff, Bs + br * 32);
        }
    };

    f4 acc[MT][NT];
    #pragma unroll
    for (int i = 0; i < MT; i++)
        #pragma unroll
        for (int j = 0; j < NT; j++)
            acc[i][j] = (f4){0.f, 0.f, 0.f, 0.f};

    stage(0, 0);
    if (KT > 1) stage(1, 32);
    int sb = 0;
    int sw2 = (lrow >> 1) & 3;
    for (int kt = 0; kt < KT; kt++) {
        // retire this iter's stage batch; keep next iter's NPF loads in flight
        if (kt + 1 < KT) {
            if constexpr (NPF == 6)
                asm volatile("s_waitcnt vmcnt(6) lgkmcnt(0)\ns_barrier" ::: "memory");
            else if constexpr (NPF == 2)
                asm volatile("s_waitcnt vmcnt(2) lgkmcnt(0)\ns_barrier" ::: "memory");
            else
                asm volatile("s_waitcnt vmcnt(0) lgkmcnt(0)\ns_barrier" ::: "memory");
        } else {
            asm volatile("s_waitcnt vmcnt(0) lgkmcnt(0)\ns_barrier" ::: "memory");
        }
        const short* Ab = stg + sb * STG;
        const short* Bb = Ab + BM * 32;
        if (kt + 2 < KT) {
            int s2 = sb + 2; if (s2 >= 3) s2 -= 3;
            stage(s2, (kt + 2) * 32);   // lands 2 iters from now
        }
        short8 af[MT], bfr[NT];
        #pragma unroll
        for (int mt = 0; mt < MT; mt++)
            af[mt] = *(const short8*)&Ab[(wm * (MT * 16) + mt * 16 + lrow) * 32 + (quad ^ sw2) * 8];
        #pragma unroll
        for (int nt = 0; nt < NT; nt++)
            bfr[nt] = *(const short8*)&Bb[(wn * (NT * 16) + nt * 16 + lrow) * 32 + (quad ^ sw2) * 8];
        #pragma unroll
        for (int mt = 0; mt < MT; mt++)
            #pragma unroll
            for (int nt = 0; nt < NT; nt++)
                acc[mt][nt] = __builtin_amdgcn_mfma_f32_16x16x32_bf16(
                    af[mt], bfr[nt], acc[mt][nt], 0, 0, 0);
        sb = (sb + 1 == 3) ? 0 : sb + 1;
    }

    if constexpr (MT == 4) {
        // -------- coalesced epilogue via LDS (4 passes of 32 rows) --------
        __syncthreads();
        int rr = tid >> 3, c8 = tid & 7;
        #pragma unroll
        for (int p = 0; p < 4; p++) {
            if (wm == (p >> 1)) {
                #pragma unroll
                for (int mh = 0; mh < 2; mh++) {
                    int mt = 2 * (p & 1) + mh;
                    int lm = mh * 16 + quad * 4;
                    #pragma unroll
                    for (int nt = 0; nt < NT; nt++) {
                        int col = wn * (NT * 16) + nt * 16 + lrow;
                        #pragma unroll
                        for (int r = 0; r < 4; r++)
                            ep[(lm + r) * 260 + col] = acc[mt][nt][r];
                    }
                }
            }
            __syncthreads();
            int m = bm0 + p * 32 + rr;
            #pragma unroll
            for (int i = 0; i < NT; i++) {
                int ci = i * 8 + c8;
                int n = bn0 + ci * 4;
                float4 v = *(const float4*)&ep[rr * 260 + ci * 4];
                if (bias0) {
                    float4 bb = *(const float4*)&bias0[n];
                    v.x += bb.x; v.y += bb.y; v.z += bb.z; v.w += bb.w;
                }
                if (bias1) {
                    float4 bb = *(const float4*)&bias1[n];
                    v.x += bb.x; v.y += bb.y; v.z += bb.z; v.w += bb.w;
                }
                if (epi_mode == 1) {
                    float4 e = *(const float4*)(E + (size_t)(m / m_div) * N + n);
                    v.x *= e.x; v.y *= e.y; v.z *= e.z; v.w *= e.w;
                } else if (epi_mode == 2) {
                    float g = gate[m];
                    float4 mm = *(const float4*)(mi1 + (size_t)m * N + n);
                    v.x = g * mm.x + (1.f - g) * v.x;
                    v.y = g * mm.y + (1.f - g) * v.y;
                    v.z = g * mm.z + (1.f - g) * v.z;
                    v.w = g * mm.w + (1.f - g) * v.w;
                }
                if (out_f32) {
                    *(float4*)((float*)Cout + (size_t)m * N + n) = v;
                } else {
                    union { u16 u[4]; uint2 d; } o;
                    o.u[0] = f2b(v.x); o.u[1] = f2b(v.y);
                    o.u[2] = f2b(v.z); o.u[3] = f2b(v.w);
                    *(uint2*)((u16*)Cout + (size_t)m * N + n) = o.d;
                }
            }
            __syncthreads();
        }
    } else {
        // -------- direct epilogue (small tiles: write volume tiny) --------
        #pragma unroll
        for (int nt = 0; nt < NT; nt++) {
            int n = bn0 + wn * (NT * 16) + nt * 16 + lrow;
            float bv = 0.f;
            if (bias0) bv += bias0[n];
            if (bias1) bv += bias1[n];
            #pragma unroll
            for (int mt = 0; mt < MT; mt++) {
                #pragma unroll
                for (int r = 0; r < 4; r++) {
                    int m = bm0 + wm * (MT * 16) + mt * 16 + quad * 4 + r;
                    float v = acc[mt][nt][r] + bv;
                    if (epi_mode == 1) {
                        v *= E[(size_t)(m / m_div) * N + n];
                    } else if (epi_mode == 2) {
                        float g = gate[m];
                        v = g * mi1[(size_t)m * N + n] + (1.f - g) * v;
                    }
                    if (out_f32) ((float*)Cout)[(size_t)m * N + n] = v;
                    else         ((u16*)Cout)[(size_t)m * N + n] = f2b(v);
                }
            }
        }
    }
}

// ---------------------------------------------------------------- control attention
__global__ __launch_bounds__(256) void control_attn(
    const float* __restrict__ cqi, const float* __restrict__ cws,
    const float* __restrict__ Wcai, const float* __restrict__ bcai,
    float* __restrict__ ci_f32, float* __restrict__ ci_out)
{
    int b = blockIdx.x, tid = threadIdx.x;
    __shared__ float tW[512];
    __shared__ float p[128];
    __shared__ float inv_l;
    for (int d = tid; d < 512; d += 256)
        tW[d] = cqi[(size_t)b * 512 + d] * Wcai[d];
    __syncthreads();
    int wave = tid >> 6, lane = tid & 63;
    const float* cwsb = cws + (size_t)b * 128 * 512;
    for (int s = wave; s < 128; s += 4) {
        const float* row = cwsb + (size_t)s * 512 + lane * 8;
        float acc = 0.f;
        #pragma unroll
        for (int j = 0; j < 8; j++) acc += tW[lane * 8 + j] * row[j];
        acc = wave_reduce_sum(acc);
        if (lane == 0) p[s] = acc + bcai[0];
    }
    __syncthreads();
    if (tid == 0) {
        float m = -1e30f;
        for (int s = 0; s < 128; s++) m = fmaxf(m, p[s]);
        float l = 0.f;
        for (int s = 0; s < 128; s++) { float e = __expf(p[s] - m); p[s] = e; l += e; }
        inv_l = 1.f / l;
    }
    __syncthreads();
    float inv = inv_l;
    for (int d = tid; d < 512; d += 256) {
        float acc = 0.f;
        for (int s = 0; s < 128; s++) acc += p[s] * cwsb[(size_t)s * 512 + d];
        acc *= inv;
        ci_f32[(size_t)b * 512 + d] = acc;
        ci_out[(size_t)b * 512 + d] = acc;
    }
}

// ---------------------------------------------------------------- read reduce
// per (b,d): softmax over H of rai (online), softmax over W of probs, dot with K(bf16)
__global__ __launch_bounds__(256) void read_reduce(
    const u16* __restrict__ rai, const u16* __restrict__ Kb, u16* __restrict__ ri)
{
    int b = blockIdx.x >> 1;
    int d = ((blockIdx.x & 1) << 8) + threadIdx.x;
    const u16* rb = rai + (size_t)b * 196 * 512 + d;
    const u16* kb = Kb + (size_t)b * 196 * 512 + d;
    float m1[14], il1[14];
    #pragma unroll
    for (int w = 0; w < 14; w++) {
        float m = -1e30f, s = 0.f;
        #pragma unroll
        for (int h = 0; h < 14; h++) {
            float v = b2f(rb[(size_t)(h * 14 + w) * 512]);
            float nm = fmaxf(m, v);
            s = s * __expf(m - nm) + __expf(v - nm);
            m = nm;
        }
        m1[w] = m; il1[w] = 1.f / s;
    }
    float acc = 0.f;
    #pragma unroll
    for (int h = 0; h < 14; h++) {
        float pv[14], ss = 0.f;
        #pragma unroll
        for (int w = 0; w < 14; w++) {
            float pr = __expf(b2f(rb[(size_t)(h * 14 + w) * 512]) - m1[w]) * il1[w];
            float e = __expf(pr);
            pv[w] = e; ss += e;
        }
        float il2 = 1.f / ss;
        #pragma unroll
        for (int w = 0; w < 14; w++)
            acc += pv[w] * il2 * b2f(kb[(size_t)(h * 14 + w) * 512]);
    }
    ri[(size_t)b * 512 + d] = f2b(acc);
}

// ---------------------------------------------------------------- write attention + gate
__global__ __launch_bounds__(256) void write_attn(
    const float* __restrict__ ci_f32, const float* __restrict__ C_past,
    const float* __restrict__ M_past,
    const float* __restrict__ Wwcc, const float* __restrict__ bwcc,
    const float* __restrict__ Wwci, const float* __restrict__ bwci,
    u16* __restrict__ mi_sa, float* __restrict__ gate)
{
    int b = blockIdx.x, tid = threadIdx.x;
    __shared__ float c[512];
    __shared__ float pt[12];
    __shared__ float red[256];
    for (int d = tid; d < 512; d += 256) c[d] = ci_f32[(size_t)b * 512 + d];
    __syncthreads();
    float g = 0.f;
    for (int d = tid; d < 512; d += 256) g += c[d] * Wwci[d];
    red[tid] = g;
    __syncthreads();
    for (int s = 128; s > 0; s >>= 1) {
        if (tid < s) red[tid] += red[tid + s];
        __syncthreads();
    }
    int wave = tid >> 6, lane = tid & 63;
    const float* cp = C_past + (size_t)b * 12 * 512;
    for (int t = wave; t < 12; t += 4) {
        float acc = 0.f;
        #pragma unroll
        for (int j = 0; j < 8; j++) {
            int d = lane * 8 + j;
            acc += c[d] * Wwcc[d] * cp[(size_t)t * 512 + d];
        }
        acc = wave_reduce_sum(acc);
        if (lane == 0) pt[t] = acc + bwcc[0];
    }
    __syncthreads();
    if (tid == 0) {
        float m = -1e30f;
        for (int t = 0; t < 12; t++) m = fmaxf(m, pt[t]);
        float l = 0.f;
        for (int t = 0; t < 12; t++) { float e = __expf(pt[t] - m); pt[t] = e; l += e; }
        float invl = 1.f / l;
        for (int t = 0; t < 12; t++) pt[t] *= invl;
        gate[b] = 1.f / (1.f + __expf(-(red[0] + bwci[0])));
    }
    __syncthreads();
    const float* mp = M_past + (size_t)b * 12 * 512;
    for (int d = tid; d < 512; d += 256) {
        float acc = 0.f;
        #pragma unroll
        for (int t = 0; t < 12; t++) acc += pt[t] * mp[(size_t)t * 512 + d];
        mi_sa[(size_t)b * 512 + d] = f2b(acc);
    }
}

// ---------------------------------------------------------------- launch
extern "C" void kernel_launch(void* const* d_in, const int* in_sizes, int n_in,
                              void* d_out, int out_size, void* d_ws, size_t ws_size,
                              hipStream_t stream) {
    (void)in_sizes; (void)n_in; (void)out_size;
    const int B = 256, D = 512, HW = 196;

    const float* ci_1   = (const float*)d_in[0];
    const float* mi_1   = (const float*)d_in[1];
    const float* q      = (const float*)d_in[2];
    const float* cws    = (const float*)d_in[3];
    const float* Kin    = (const float*)d_in[4];
    const float* C_past = (const float*)d_in[5];
    const float* M_past = (const float*)d_in[6];
    const float* W_cq   = (const float*)d_in[7];
    const float* b_cq   = (const float*)d_in[8];
    const float* W_cqi  = (const float*)d_in[9];
    const float* b_cqi  = (const float*)d_in[10];
    const float* W_cai  = (const float*)d_in[11];
    const float* b_cai  = (const float*)d_in[12];
    const float* W_rm   = (const float*)d_in[13];
    const float* b_rm   = (const float*)d_in[14];
    const float* W_rk   = (const float*)d_in[15];
    const float* b_rk   = (const float*)d_in[16];
    const float* W_rik  = (const float*)d_in[17];
    const float* b_rik  = (const float*)d_in[18];
    const float* W_rci  = (const float*)d_in[19];
    const float* b_rci  = (const float*)d_in[20];
    const float* W_wrm  = (const float*)d_in[21];
    const float* b_wrm  = (const float*)d_in[22];
    const float* W_wcc  = (const float*)d_in[23];
    const float* b_wcc  = (const float*)d_in[24];
    const float* W_wsa  = (const float*)d_in[25];
    const float* b_wsa  = (const float*)d_in[26];
    const float* W_winfo= (const float*)d_in[27];
    const float* b_winfo= (const float*)d_in[28];
    const float* W_wci  = (const float*)d_in[29];
    const float* b_wci  = (const float*)d_in[30];

    float* out_ci = (float*)d_out;
    float* out_mi = (float*)d_out + (size_t)B * D;

    char* ws = (char*)d_ws;
    size_t off = 0;
    auto alloc = [&](size_t bytes) -> void* {
        void* p = ws + off; off += (bytes + 255) & ~(size_t)255; return p;
    };
    u16* wt_cq    = (u16*)alloc((size_t)D * D * 2);
    u16* wt_cqi   = (u16*)alloc((size_t)D * 2 * D * 2);
    u16* wt_rm    = (u16*)alloc((size_t)D * D * 2);
    u16* wt_rk    = (u16*)alloc((size_t)D * D * 2);
    u16* wt_rik   = (u16*)alloc((size_t)D * 2 * D * 2);
    u16* wt_rci   = (u16*)alloc((size_t)D * D * 2);
    u16* wt_wrm   = (u16*)alloc((size_t)D * 2 * D * 2);
    u16* wt_wsi   = (u16*)alloc((size_t)D * 2 * D * 2);
    u16* qb       = (u16*)alloc((size_t)B * D * 2);
    u16* cib      = (u16*)alloc((size_t)B * D * 2);
    u16* mib      = (u16*)alloc((size_t)B * D * 2);
    u16* qi_buf   = (u16*)alloc((size_t)B * D * 2);
    float* cqi_f32= (float*)alloc((size_t)B * D * 4);
    float* rm_f32 = (float*)alloc((size_t)B * D * 4);
    float* ci_f32 = (float*)alloc((size_t)B * D * 4);
    u16* ri_buf   = (u16*)alloc((size_t)B * D * 2);
    u16* misa_buf = (u16*)alloc((size_t)B * D * 2);
    u16* minfo_buf= (u16*)alloc((size_t)B * D * 2);
    float* gate_b = (float*)alloc((size_t)B * 4);

    int chunk_b = 256;
    while (chunk_b > 32) {
        size_t need = off + 3 * (((size_t)chunk_b * HW * D * 2 + 255) & ~(size_t)255);
        if (need <= ws_size) break;
        chunk_b >>= 1;
    }
    u16* kbf  = (u16*)alloc((size_t)chunk_b * HW * D * 2);
    u16* big1 = (u16*)alloc((size_t)chunk_b * HW * D * 2);
    u16* big2 = (u16*)alloc((size_t)chunk_b * HW * D * 2);

    dim3 tb(32, 8);
    transpose_k<<<dim3(D / 32, D / 32), tb, 0, stream>>>(W_cq,   wt_cq,  D,     D, D,     0);
    transpose_k<<<dim3(2 * D / 32, D / 32), tb, 0, stream>>>(W_cqi, wt_cqi, 2 * D, D, 2 * D, 0);
    transpose_k<<<dim3(D / 32, D / 32), tb, 0, stream>>>(W_rm,   wt_rm,  D,     D, D,     0);
    transpose_k<<<dim3(D / 32, D / 32), tb, 0, stream>>>(W_rk,   wt_rk,  D,     D, D,     0);
    transpose_k<<<dim3(2 * D / 32, D / 32), tb, 0, stream>>>(W_rik, wt_rik, 2 * D, D, 2 * D, 0);
    transpose_k<<<dim3(D / 32, D / 32), tb, 0, stream>>>(W_rci,  wt_rci, D,     D, D,     0);
    transpose_k<<<dim3(2 * D / 32, D / 32), tb, 0, stream>>>(W_wrm, wt_wrm, 2 * D, D, 2 * D, 0);
    transpose_k<<<dim3(D / 32, D / 32), tb, 0, stream>>>(W_wsa,  wt_wsi, D,     D, 2 * D, 0);
    transpose_k<<<dim3(D / 32, D / 32), tb, 0, stream>>>(W_winfo,wt_wsi, D,     D, 2 * D, D);

    int nbd = B * D;
    conv_f32_bf16<<<nbd / 1024, 256, 0, stream>>>(q, qb, nbd);
    conv_f32_bf16<<<nbd / 1024, 256, 0, stream>>>(ci_1, cib, nbd);
    conv_f32_bf16<<<nbd / 1024, 256, 0, stream>>>(mi_1, mib, nbd);

    dim3 gsmall(D / 64, B / 64); // (8, 4) = 32 blocks

    gemm_mfma<2,2><<<gsmall, 256, 0, stream>>>(qb, nullptr, B, D, 0, D, wt_cq, b_cq, nullptr,
                                               0, nullptr, 1, nullptr, nullptr, qi_buf, 0);
    gemm_mfma<2,2><<<gsmall, 256, 0, stream>>>(cib, qi_buf, B, D, D, D, wt_cqi, b_cqi, nullptr,
                                               0, nullptr, 1, nullptr, nullptr, cqi_f32, 1);
    control_attn<<<B, 256, 0, stream>>>(cqi_f32, cws, W_cai, b_cai, ci_f32, out_ci);
    gemm_mfma<2,2><<<gsmall, 256, 0, stream>>>(mib, nullptr, B, D, 0, D, wt_rm, b_rm, nullptr,
                                               0, nullptr, 1, nullptr, nullptr, rm_f32, 1);

    for (int c = 0; c < B; c += chunk_b) {
        int mrows = chunk_b * HW;
        const float* Kc = Kin + (size_t)c * HW * D;
        conv_f32_bf16<<<(mrows * D) / 1024, 256, 0, stream>>>(Kc, kbf, mrows * D);
        dim3 gbig(D / 256, mrows / 128);
        gemm_mfma<4,8><<<gbig, 256, 0, stream>>>(kbf, nullptr, mrows, D, 0, D, wt_rk, b_rk, nullptr,
                                                 1, rm_f32 + (size_t)c * D, HW, nullptr, nullptr,
                                                 big1, 0);
        gemm_mfma<4,8><<<gbig, 256, 0, stream>>>(big1, kbf, mrows, D, D, D, wt_rik, b_rik, nullptr,
                                                 1, ci_f32 + (size_t)c * D, HW, nullptr, nullptr,
                                                 big2, 0);
        gemm_mfma<4,8><<<gbig, 256, 0, stream>>>(big2, nullptr, mrows, D, 0, D, wt_rci, b_rci, nullptr,
                                                 0, nullptr, 1, nullptr, nullptr, big1, 0);
        read_reduce<<<chunk_b * 2, 256, 0, stream>>>(big1, kbf, ri_buf + (size_t)c * D);
    }

    gemm_mfma<2,2><<<gsmall, 256, 0, stream>>>(ri_buf, mib, B, D, D, D, wt_wrm, b_wrm, nullptr,
                                               0, nullptr, 1, nullptr, nullptr, minfo_buf, 0);
    write_attn<<<B, 256, 0, stream>>>(ci_f32, C_past, M_past, W_wcc, b_wcc, W_wci, b_wci,
                                      misa_buf, gate_b);
    gemm_mfma<2,2><<<gsmall, 256, 0, stream>>>(misa_buf, minfo_buf, B, D, D, D, wt_wsi,
                                               b_wsa, b_winfo, 2, nullptr, 1, gate_b, mi_1,
                                               out_mi, 1);
}